// Round 9
// baseline (142.738 us; speedup 1.0000x reference)
//
#include <hip/hip_runtime.h>
#include <cstdint>
#include <cstddef>

typedef unsigned long long u64;

// ---------------- problem constants ----------------
constexpr int Bn   = 8;
constexpr int Pn   = 2000;
constexpr int Cn   = 81;
constexpr int CM1  = 80;
constexpr int KPRE = 2048;
constexpr int NDET = 100;
constexpr int SECP = 8;              // proposals per K1 block (1 per wave)
constexpr int NSEC2 = Pn / SECP;     // 250 sections per image
constexpr int SSLOT = 160;           // slice stride (hard max 8*19 = 152)
constexpr int NSEG = 4;              // sort segments per image
constexpr int RUNL = 2048;           // sorted run length per segment (exact top-2048)
constexpr int K2CAP = 4096;          // per-segment raw cap (mean ~1775)
constexpr float W_IMG = 1333.0f;
constexpr float H_IMG = 800.0f;
constexpr float XFORM_CLIP = 4.135166556742356f; // log(1000/16)
constexpr float NMS_OFF = 1334.0f;               // max(W,H)+1

// ---------------- ws layout (bytes) ---- no zero-init needed anywhere ------
// (done[] is zeroed by k1 every launch; ws poison between iterations is fine)
constexpr size_t OFF_SL   = 0;                                   // Bn*NSEC2*SSLOT u64
constexpr size_t OFF_SC   = (size_t)Bn * NSEC2 * SSLOT * 8;      // Bn*NSEC2 int
constexpr size_t OFF_RUNS = OFF_SC + (size_t)Bn * NSEC2 * 4;     // Bn*NSEG*RUNL u64
constexpr size_t OFF_DONE = OFF_RUNS + (size_t)Bn * NSEG * RUNL * 8; // Bn int

__device__ __forceinline__ void decode_clip(const float4 rv, float w, float h,
                                            float cx, float cy, float out[4]) {
  float dx = rv.x / 10.0f;
  float dy = rv.y / 10.0f;
  float dw = fminf(rv.z / 5.0f, XFORM_CLIP);
  float dh = fminf(rv.w / 5.0f, XFORM_CLIP);
  float pcx = dx * w + cx;
  float pcy = dy * h + cy;
  float pw = expf(dw) * w;
  float ph = expf(dh) * h;
  out[0] = fminf(fmaxf(pcx - 0.5f * pw, 0.0f), W_IMG);
  out[1] = fminf(fmaxf(pcy - 0.5f * ph, 0.0f), H_IMG);
  out[2] = fminf(fmaxf(pcx + 0.5f * pw, 0.0f), W_IMG);
  out[3] = fminf(fmaxf(pcy + 0.5f * ph, 0.0f), H_IMG);
}

// decode a candidate key into raw clipped box + label + score
__device__ __forceinline__ void key_decode(u64 key, int b,
                                           const float* __restrict__ reg,
                                           const float* __restrict__ props,
                                           float bx[4], int& label, float& sc) {
  sc = __uint_as_float((unsigned)(key >> 32));
  bx[0] = bx[1] = bx[2] = bx[3] = 0.0f;
  label = 0;
  if (key != 0ull) {
    int m = (int)(0xFFFFFFFFu - (unsigned)key);
    int p = m / CM1;
    int c = m - p * CM1 + 1;
    int nidx = b * Pn + p;
    const float4 pb = *reinterpret_cast<const float4*>(props + (size_t)nidx * 4);
    float w = pb.z - pb.x, h = pb.w - pb.y;
    float cx = pb.x + 0.5f * w, cy = pb.y + 0.5f * h;
    float4 rv = *reinterpret_cast<const float4*>(reg + (size_t)nidx * (Cn * 4) + c * 4);
    decode_clip(rv, w, h, cx, cy, bx);
    label = c;
  }
}

// ---------------- K1: softmax + decode + valid -> per-section slices --------
// 512 threads = 8 waves, ONE proposal per wave (unchanged from R8).
// Blocks 0..7 additionally zero done[0..7] for this launch.
__global__ __launch_bounds__(512) void
k1_score(const float* __restrict__ logits, const float* __restrict__ reg,
         const float* __restrict__ props, u64* __restrict__ slices,
         int* __restrict__ scnt, int* __restrict__ done) {
  int blk = blockIdx.x, t = threadIdx.x, lane = t & 63, wv = t >> 6;  // 0..7
  int b = blk / NSEC2, sec = blk % NSEC2;
  __shared__ u64 cbuf[SSLOT];
  __shared__ int cnt_sh;
  if (t == 0) cnt_sh = 0;
  if (blk < Bn && t == 0) done[blk] = 0;   // reset arrival counters
  __syncthreads();

  {
    int p = sec * SECP + wv;
    int wid = b * Pn + p;
    const float* lg = logits + (size_t)wid * Cn;
    float x0 = lg[lane];
    float x1 = (lane < Cn - 64) ? lg[64 + lane] : -3.4e38f;
    float mx = fmaxf(x0, x1);
    for (int m = 32; m; m >>= 1) mx = fmaxf(mx, __shfl_xor(mx, m, 64));
    float e0 = expf(x0 - mx);
    float e1 = (lane < Cn - 64) ? expf(x1 - mx) : 0.0f;
    float ssum = e0 + e1;
    for (int m = 32; m; m >>= 1) ssum += __shfl_xor(ssum, m, 64);

    const float4 pb = *reinterpret_cast<const float4*>(props + (size_t)wid * 4);
    float w = pb.z - pb.x, h = pb.w - pb.y;
    float cx = pb.x + 0.5f * w, cy = pb.y + 0.5f * h;
    const float* rrow = reg + (size_t)wid * (Cn * 4);

    u64 key0 = 0ull, key1 = 0ull;
    if (lane >= 1) {                     // class c = lane (1..63)
      float sc = e0 / ssum;
      if (sc > 0.05f) {
        float4 rv = *reinterpret_cast<const float4*>(rrow + lane * 4);
        float bx[4];
        decode_clip(rv, w, h, cx, cy, bx);
        if ((bx[2] - bx[0] >= 0.01f) && (bx[3] - bx[1] >= 0.01f)) {
          unsigned m = (unsigned)(p * CM1 + (lane - 1));
          key0 = ((u64)__float_as_uint(sc) << 32) | (0xFFFFFFFFu - m);
        }
      }
    }
    if (lane < Cn - 64) {                // class c = 64+lane (64..80)
      int c = 64 + lane;
      float sc = e1 / ssum;
      if (sc > 0.05f) {
        float4 rv = *reinterpret_cast<const float4*>(rrow + c * 4);
        float bx[4];
        decode_clip(rv, w, h, cx, cy, bx);
        if ((bx[2] - bx[0] >= 0.01f) && (bx[3] - bx[1] >= 0.01f)) {
          unsigned m = (unsigned)(p * CM1 + (c - 1));
          key1 = ((u64)__float_as_uint(sc) << 32) | (0xFFFFFFFFu - m);
        }
      }
    }
    u64 bal0 = __ballot(key0 != 0ull);
    u64 bal1 = __ballot(key1 != 0ull);
    int tot = __popcll(bal0) + __popcll(bal1);
    if (tot) {
      int base = 0;
      if (lane == 0) base = atomicAdd(&cnt_sh, tot);   // LDS atomic only
      base = __shfl(base, 0, 64);
      int r0 = __popcll(bal0 & ((1ull << lane) - 1ull));
      int r1 = __popcll(bal0) + __popcll(bal1 & ((1ull << lane) - 1ull));
      if (key0) cbuf[base + r0] = key0;
      if (key1) cbuf[base + r1] = key1;
    }
  }
  __syncthreads();
  int n = cnt_sh;                         // <= 152
  for (int i = t; i < n; i += 512) slices[(size_t)blk * SSLOT + i] = cbuf[i];
  if (t == 0) scnt[blk] = n;
}

// in-place reg-staged merge-path round over LDS (desc, A-priority, exact);
// used for the per-segment 4096 -> top-2048 truncation
template <int CHV>
__device__ __forceinline__ void mp_round(u64* buf, int base, int nA, int nB,
                                         int outLen, int tid) {
  const u64* A = buf + base;
  const u64* B = buf + base + nA;
  int d = tid * CHV;
  u64 rg[CHV];
  int cnt = 0;
  if (d < outLen) {
    int lo = max(0, d - nB), hi = min(d, nA);
    while (lo < hi) {
      int mid = (lo + hi) >> 1;
      if (A[mid] >= B[d - 1 - mid]) lo = mid + 1; else hi = mid;
    }
    int i = lo, j = d - lo;
    for (int e = 0; e < CHV && d + e < outLen; e++) {
      u64 v;
      if (j >= nB || (i < nA && A[i] >= B[j])) v = A[i++];
      else v = B[j++];
      rg[cnt++] = v;
    }
  }
  __syncthreads();
  for (int e = 0; e < cnt; e++) buf[base + d + e] = rg[e];
  __syncthreads();
}

// in-place merge round over a 4096-element LDS buffer: pairs of sorted len/2
// runs -> sorted len runs. CHV=4 keeps cursors 32 B apart (bank-spread).
template <int CHV>
__device__ __forceinline__ void mp_seg_round(u64* buf, int len, int cnt, int t) {
  int tps = len / CHV;           // threads per segment (1024*CHV == 4096)
  int seg = t / tps;
  int tid = t - seg * tps;
  int base = seg * len;
  bool act = (base < cnt);
  int nA = len >> 1;
  int d = tid * CHV;
  u64 rg[CHV];
  if (act) {
    const u64* A = buf + base;
    const u64* B = buf + base + nA;
    int lo = max(0, d - nA), hi = min(d, nA);
    while (lo < hi) {
      int mid = (lo + hi) >> 1;
      if (A[mid] >= B[d - 1 - mid]) lo = mid + 1; else hi = mid;
    }
    int i = lo, j = d - lo;
    #pragma unroll
    for (int e = 0; e < CHV; e++) {
      u64 v;
      if (j >= nA || (i < nA && A[i] >= B[j])) v = A[i++];
      else v = B[j++];
      rg[e] = v;
    }
  }
  __syncthreads();
  if (act) {
    #pragma unroll
    for (int e = 0; e < CHV; e++) buf[base + d + e] = rg[e];
  }
  __syncthreads();
}

// wave-level compacting append of one 64-wide chunk
__device__ __forceinline__ void append_chunk(u64 key, bool valid, u64* buf,
                                             int* cnt_sh, int lane) {
  u64 bal = __ballot(valid);
  int tot = __popcll(bal);
  if (tot) {
    int base = 0;
    if (lane == 0) base = atomicAdd(cnt_sh, tot);
    base = __shfl(base, 0, 64);
    int rank = __popcll(bal & ((1ull << lane) - 1ull));
    int pos = base + rank;
    if (valid && pos < K2CAP) buf[pos] = key;
  }
}

// ---------------- K2: segment sort + last-arrival merge/NMS -----------------
// 32 blocks (8 images x 4 segments). Every block sorts its segment to an
// exact top-2048 run in global. The LAST of an image's 4 blocks to finish
// (device-scope arrival counter) continues straight into the merge + NMS +
// output phase for that image — no third launch, no grid-wide drain.
__global__ __launch_bounds__(1024) void
k2_sortnms(const u64* __restrict__ slices, const int* __restrict__ scnt,
           u64* __restrict__ runs, int* __restrict__ done,
           const float* __restrict__ reg, const float* __restrict__ props,
           float* __restrict__ out) {
  int blk = blockIdx.x, t = threadIdx.x, lane = t & 63, w = t >> 6;  // 16 waves
  int b = blk >> 2, seg = blk & 3;
  // ---- LDS union: phase A uses bufS[0..4096); phase B uses everything ----
  __shared__ u64 bufS[NSEG * RUNL];    // 64 KB
  __shared__ u64 bufD[NSEG * RUNL];    // 64 KB
  __shared__ u64 maskb[256][4];        // 8 KB
  __shared__ u64 keepw[KPRE / 64];     // 256 B
  __shared__ int accI[NDET];
  __shared__ int lcnt2[63];
  __shared__ int cnt_sh, kcnt_sh, old_sh;
  u64* buf = bufS;                     // phase-A sort buffer (4096 u64)
  float4* obox = (float4*)bufD;

  // ======== phase A: per-segment stream -> sort -> exact top-2048 run ======
  int s0 = seg * 62 + min(seg, 2);        // 63,63,62,62 sections
  int ns = 62 + (seg < 2 ? 1 : 0);
  if (t == 0) cnt_sh = 0;
  if (t < ns) lcnt2[t] = scnt[b * NSEC2 + s0 + t];
  __syncthreads();

  // prefetched stream of this segment's sections (16 waves, ~4 iters/wave)
  {
    int sl = w;
    int n0 = 0; u64 kv = 0ull;
    if (sl < ns) {
      n0 = lcnt2[sl];
      if (lane < n0) kv = slices[(size_t)(b * NSEC2 + s0 + sl) * SSLOT + lane];
    }
    while (sl < ns) {
      int nx = sl + 16;
      int n1 = 0; u64 kn = 0ull;
      if (nx < ns) {                      // issue next section's load NOW
        n1 = lcnt2[nx];
        if (lane < n1)
          kn = slices[(size_t)(b * NSEC2 + s0 + nx) * SSLOT + lane];
      }
      append_chunk(kv, (lane < n0) && (kv != 0ull), buf, &cnt_sh, lane);
      for (int i0 = 64; i0 < n0; i0 += 64) {   // sections with > 64 cands
        int i = i0 + lane;
        u64 ke = (i < n0) ? slices[(size_t)(b * NSEC2 + s0 + sl) * SSLOT + i]
                          : 0ull;
        append_chunk(ke, ke != 0ull, buf, &cnt_sh, lane);
      }
      sl = nx; n0 = n1; kv = kn;
    }
  }
  __syncthreads();
  int cnt = min(cnt_sh, K2CAP);
  for (int i = cnt + t; i < K2CAP; i += 1024) buf[i] = 0ull;
  __syncthreads();

  // 64-wide register bitonic sorts (desc), zero barriers
  for (int r = w; (r << 6) < cnt; r += 16) {
    u64 v = buf[(r << 6) | lane];
    #pragma unroll
    for (int k = 2; k <= 64; k <<= 1) {
      #pragma unroll
      for (int j = k >> 1; j > 0; j >>= 1) {
        u64 o = __shfl_xor(v, j, 64);
        bool dir = ((lane & k) == 0);      // descending block
        bool lower = ((lane & j) == 0);
        u64 mn = (v < o) ? v : o;
        u64 mx = (v < o) ? o : v;
        v = (dir == lower) ? mx : mn;
      }
    }
    buf[(r << 6) | lane] = v;
  }
  __syncthreads();

  // guarded merge tree 64 -> 2048, then truncate 4096 -> top-2048
  if (cnt > 64)   mp_seg_round<4>(buf, 128, cnt, t);
  if (cnt > 128)  mp_seg_round<4>(buf, 256, cnt, t);
  if (cnt > 256)  mp_seg_round<4>(buf, 512, cnt, t);
  if (cnt > 512)  mp_seg_round<4>(buf, 1024, cnt, t);
  if (cnt > 1024) mp_seg_round<4>(buf, 2048, cnt, t);
  if (cnt > 2048) mp_round<2>(buf, 0, 2048, 2048, 2048, t);

  // write the (zero-padded) sorted top-2048 run
  for (int i = t; i < RUNL; i += 1024)
    runs[(size_t)blk * RUNL + i] = buf[i];

  // ======== arrival: last of the image's 4 blocks continues to phase B =====
  __threadfence();                        // release run writes device-wide
  if (t == 0) old_sh = atomicAdd(&done[b], 1);
  __syncthreads();
  if ((old_sh & 3) != 3) return;          // not last: done
  __threadfence();                        // acquire other blocks' run writes

  // ======== phase B: merge 4 runs -> top-2048 -> decode -> NMS -> out ======
  for (int i = t; i < NSEG * RUNL; i += 1024)
    bufS[i] = runs[(size_t)b * NSEG * RUNL + i];
  __syncthreads();

  // round 1: two independent pair merges (2048+2048 -> 4096), S -> D, CHV=4
  #pragma unroll
  for (int p = 0; p < 2; p++) {
    const u64* A = bufS + p * 4096;
    const u64* B = A + 2048;
    int d = t * 4;
    int lo = max(0, d - 2048), hi = min(d, 2048);
    while (lo < hi) {
      int mid = (lo + hi) >> 1;
      if (A[mid] >= B[d - 1 - mid]) lo = mid + 1; else hi = mid;
    }
    int i = lo, j = d - lo;
    #pragma unroll
    for (int e = 0; e < 4; e++) {
      u64 v;
      if (j >= 2048 || (i < 2048 && A[i] >= B[j])) v = A[i++];
      else v = B[j++];
      bufD[p * 4096 + d + e] = v;
    }
  }
  __syncthreads();
  // round 2: truncating merge (4096 + 4096 -> top-2048), D -> S, CHV=2
  {
    const u64* A = bufD;
    const u64* B = bufD + 4096;
    int d = t * 2;
    int lo = max(0, d - 4096), hi = min(d, 4096);
    while (lo < hi) {
      int mid = (lo + hi) >> 1;
      if (A[mid] >= B[d - 1 - mid]) lo = mid + 1; else hi = mid;
    }
    int i = lo, j = d - lo;
    #pragma unroll
    for (int e = 0; e < 2; e++) {
      u64 v;
      if (j >= 4096 || (i < 4096 && A[i] >= B[j])) v = A[i++];
      else v = B[j++];
      bufS[d + e] = v;                   // final keys in bufS[0..2048)
    }
  }
  __syncthreads();

  // keepw init + decode obox (bufD free now; keys stay live in bufS)
  u64 k0 = bufS[t], k1v = bufS[t + 1024];
  {
    u64 bal = __ballot(k0 != 0ull);
    if (lane == 0) keepw[w] = bal;
    bal = __ballot(k1v != 0ull);
    if (lane == 0) keepw[16 + w] = bal;
  }
  __syncthreads();
  #pragma unroll
  for (int s = 0; s < 2; s++) {
    int j = t + s * 1024;
    u64 key = s ? k1v : k0;
    float bx[4]; int label; float sc;
    key_decode(key, b, reg, props, bx, label, sc);
    float off = (float)label * NMS_OFF;
    obox[j] = make_float4(bx[0] + off, bx[1] + off, bx[2] + off, bx[3] + off);
  }
  __syncthreads();

  // windowed bitmask greedy NMS with early exit
  int kcount = 0;
  for (int w0 = 0; w0 < KPRE && kcount < NDET; w0 += 256) {
    // step1: suppress window cols by previously accepted boxes
    if (w0 > 0 && kcount > 0) {
      if (t < 256) {
        int j = w0 + t;
        u64 kwv = keepw[j >> 6];
        bool alive = (kwv >> (j & 63)) & 1ull;
        if (alive) {
          float4 jb = obox[j];
          float jar = fmaxf(jb.z - jb.x, 0.0f) * fmaxf(jb.w - jb.y, 0.0f);
          for (int a = 0; a < kcount; a++) {
            float4 ab = obox[accI[a]];
            float ix1 = fmaxf(ab.x, jb.x), iy1 = fmaxf(ab.y, jb.y);
            float ix2 = fminf(ab.z, jb.z), iy2 = fminf(ab.w, jb.w);
            float iw = fmaxf(ix2 - ix1, 0.0f), ih = fmaxf(iy2 - iy1, 0.0f);
            float inter = iw * ih;
            if (inter > 0.0f) {
              float aar = fmaxf(ab.z - ab.x, 0.0f) * fmaxf(ab.w - ab.y, 0.0f);
              float iou = inter / fmaxf(aar + jar - inter, 1e-9f);
              if (iou > 0.5f) { alive = false; break; }
            }
          }
        }
        u64 bal = __ballot(alive);
        if (lane == 0) keepw[(w0 >> 6) + (t >> 6)] = bal;
      }
      __syncthreads();
    }
    // step2: window-internal suppression bitmask (row r = t>>2, word wd = t&3)
    {
      int r = t >> 2, wd = t & 3;
      int rgp = w0 + r;
      bool ralive = (keepw[rgp >> 6] >> (rgp & 63)) & 1ull;
      float4 rb = obox[rgp];
      float rar = fmaxf(rb.z - rb.x, 0.0f) * fmaxf(rb.w - rb.y, 0.0f);
      u64 m = 0;
      if (ralive) {
        int cb0 = w0 + wd * 64;
        for (int jj = 0; jj < 64; jj++) {
          int cg = cb0 + jj;
          float4 cb = obox[cg];
          float ix1 = fmaxf(rb.x, cb.x), iy1 = fmaxf(rb.y, cb.y);
          float ix2 = fminf(rb.z, cb.z), iy2 = fminf(rb.w, cb.w);
          float iw = fmaxf(ix2 - ix1, 0.0f), ih = fmaxf(iy2 - iy1, 0.0f);
          float inter = iw * ih;
          if (inter > 0.0f && cg > rgp) {
            float car = fmaxf(cb.z - cb.x, 0.0f) * fmaxf(cb.w - cb.y, 0.0f);
            float iou = inter / fmaxf(rar + car - inter, 1e-9f);
            if (iou > 0.5f) m |= (1ull << jj);
          }
        }
      }
      maskb[r][wd] = m;
    }
    __syncthreads();
    // step3: single-wave serial greedy reduce over the window
    if (w == 0) {
      u64 kw0 = keepw[(w0 >> 6) + 0];
      u64 kw1 = keepw[(w0 >> 6) + 1];
      u64 kw2 = keepw[(w0 >> 6) + 2];
      u64 kw3 = keepw[(w0 >> 6) + 3];
      int kc = kcount;
      #pragma unroll
      for (int wq = 0; wq < 4; wq++) {
        u64 cw = (wq == 0) ? kw0 : (wq == 1) ? kw1 : (wq == 2) ? kw2 : kw3;
        if (cw == 0ull) continue;
        for (int rb0 = 0; rb0 < 64 && kc < NDET; rb0 += 4) {
          u64 gbits = (cw >> rb0) & 0xFull;
          int r = wq * 64 + rb0;
          u64 rm0a = maskb[r][0],   rm0b = maskb[r][1],   rm0c = maskb[r][2],   rm0d = maskb[r][3];
          u64 rm1a = maskb[r+1][0], rm1b = maskb[r+1][1], rm1c = maskb[r+1][2], rm1d = maskb[r+1][3];
          u64 rm2a = maskb[r+2][0], rm2b = maskb[r+2][1], rm2c = maskb[r+2][2], rm2d = maskb[r+2][3];
          u64 rm3a = maskb[r+3][0], rm3b = maskb[r+3][1], rm3c = maskb[r+3][2], rm3d = maskb[r+3][3];
          if (gbits == 0ull) continue;
          #pragma unroll
          for (int d = 0; d < 4; d++) {
            u64 cwq = (wq == 0) ? kw0 : (wq == 1) ? kw1 : (wq == 2) ? kw2 : kw3;
            if ((cwq >> (rb0 + d)) & 1ull) {
              if (lane == 0) accI[kc] = w0 + r + d;
              kc++;
              if (kc >= NDET) break;
              u64 ma = (d == 0) ? rm0a : (d == 1) ? rm1a : (d == 2) ? rm2a : rm3a;
              u64 mb = (d == 0) ? rm0b : (d == 1) ? rm1b : (d == 2) ? rm2b : rm3b;
              u64 mc = (d == 0) ? rm0c : (d == 1) ? rm1c : (d == 2) ? rm2c : rm3c;
              u64 md = (d == 0) ? rm0d : (d == 1) ? rm1d : (d == 2) ? rm2d : rm3d;
              kw0 &= ~ma; kw1 &= ~mb; kw2 &= ~mc; kw3 &= ~md;
            }
          }
          cw = (wq == 0) ? kw0 : (wq == 1) ? kw1 : (wq == 2) ? kw2 : kw3;
        }
      }
      if (lane == 0) {
        keepw[(w0 >> 6) + 0] = kw0;
        keepw[(w0 >> 6) + 1] = kw1;
        keepw[(w0 >> 6) + 2] = kw2;
        keepw[(w0 >> 6) + 3] = kw3;
        kcnt_sh = kc;
      }
    }
    __syncthreads();
    kcount = kcnt_sh;
  }

  // rare path: fewer than 100 kept -> backfill non-kept ascending
  if (t == 0 && kcount < NDET) {
    int run = kcount;
    for (int wq = 0; wq < KPRE / 64 && run < NDET; wq++) {
      u64 nk = ~keepw[wq];
      while (nk && run < NDET) {
        int bit2 = __ffsll((long long)nk) - 1;
        nk &= nk - 1;
        accI[run++] = wq * 64 + bit2;
      }
    }
  }
  __syncthreads();

  if (t < NDET) {
    int k = accI[t];
    bool kept = t < kcount;
    u64 key = bufS[k];                     // final merged keys live in bufS
    float bx[4]; int label; float sc;
    key_decode(key, b, reg, props, bx, label, sc);
    int oi = b * NDET + t;
    out[(size_t)oi * 4 + 0] = bx[0];
    out[(size_t)oi * 4 + 1] = bx[1];
    out[(size_t)oi * 4 + 2] = bx[2];
    out[(size_t)oi * 4 + 3] = bx[3];
    out[Bn * NDET * 4 + oi] = kept ? sc : -1.0f;
    out[Bn * NDET * 5 + oi] = (float)label;
    out[Bn * NDET * 6 + oi] = kept ? 1.0f : 0.0f;
  }
}

extern "C" void kernel_launch(void* const* d_in, const int* in_sizes, int n_in,
                              void* d_out, int out_size, void* d_ws, size_t ws_size,
                              hipStream_t stream) {
  const float* logits = (const float*)d_in[0];
  const float* reg    = (const float*)d_in[1];
  const float* props  = (const float*)d_in[2];
  float* out = (float*)d_out;
  char* ws = (char*)d_ws;

  u64* slices = (u64*)(ws + OFF_SL);
  int* scnt   = (int*)(ws + OFF_SC);
  u64* runs   = (u64*)(ws + OFF_RUNS);
  int* done   = (int*)(ws + OFF_DONE);

  k1_score<<<Bn * NSEC2, 512, 0, stream>>>(logits, reg, props, slices, scnt, done);
  k2_sortnms<<<Bn * NSEG, 1024, 0, stream>>>(slices, scnt, runs, done,
                                             reg, props, out);
}

// Round 11
// 124.573 us; speedup vs baseline: 1.1458x; 1.1458x over previous
//
#include <hip/hip_runtime.h>
#include <cstdint>
#include <cstddef>

typedef unsigned long long u64;

// ---------------- problem constants ----------------
constexpr int Bn   = 8;
constexpr int Pn   = 2000;
constexpr int Cn   = 81;
constexpr int CM1  = 80;
constexpr int KPRE = 2048;
constexpr int NDET = 100;
constexpr int SECP = 8;              // proposals per K1 block (1 per wave)
constexpr int NSEC2 = Pn / SECP;     // 250 sections per image
constexpr int SSLOT = 160;           // slice stride (hard max 8*19 = 152)
constexpr int NSEG = 4;              // sort segments per image
constexpr int RUNL = 2048;           // sorted run length per segment (exact top-2048)
constexpr int K2CAP = 4096;          // per-segment raw cap (mean ~1775)
constexpr float W_IMG = 1333.0f;
constexpr float H_IMG = 800.0f;
constexpr float XFORM_CLIP = 4.135166556742356f; // log(1000/16)
constexpr float NMS_OFF = 1334.0f;               // max(W,H)+1

// ---------------- ws layout (bytes) ---- no zero-init needed anywhere ------
constexpr size_t OFF_SL   = 0;                                   // Bn*NSEC2*SSLOT u64
constexpr size_t OFF_SC   = (size_t)Bn * NSEC2 * SSLOT * 8;      // Bn*NSEC2 int
constexpr size_t OFF_RUNS = OFF_SC + (size_t)Bn * NSEC2 * 4;     // Bn*NSEG*RUNL u64

__device__ __forceinline__ void decode_clip(const float4 rv, float w, float h,
                                            float cx, float cy, float out[4]) {
  float dx = rv.x / 10.0f;
  float dy = rv.y / 10.0f;
  float dw = fminf(rv.z / 5.0f, XFORM_CLIP);
  float dh = fminf(rv.w / 5.0f, XFORM_CLIP);
  float pcx = dx * w + cx;
  float pcy = dy * h + cy;
  float pw = expf(dw) * w;
  float ph = expf(dh) * h;
  out[0] = fminf(fmaxf(pcx - 0.5f * pw, 0.0f), W_IMG);
  out[1] = fminf(fmaxf(pcy - 0.5f * ph, 0.0f), H_IMG);
  out[2] = fminf(fmaxf(pcx + 0.5f * pw, 0.0f), W_IMG);
  out[3] = fminf(fmaxf(pcy + 0.5f * ph, 0.0f), H_IMG);
}

// decode a candidate key into raw clipped box + label + score
__device__ __forceinline__ void key_decode(u64 key, int b,
                                           const float* __restrict__ reg,
                                           const float* __restrict__ props,
                                           float bx[4], int& label, float& sc) {
  sc = __uint_as_float((unsigned)(key >> 32));
  bx[0] = bx[1] = bx[2] = bx[3] = 0.0f;
  label = 0;
  if (key != 0ull) {
    int m = (int)(0xFFFFFFFFu - (unsigned)key);
    int p = m / CM1;
    int c = m - p * CM1 + 1;
    int nidx = b * Pn + p;
    const float4 pb = *reinterpret_cast<const float4*>(props + (size_t)nidx * 4);
    float w = pb.z - pb.x, h = pb.w - pb.y;
    float cx = pb.x + 0.5f * w, cy = pb.y + 0.5f * h;
    float4 rv = *reinterpret_cast<const float4*>(reg + (size_t)nidx * (Cn * 4) + c * 4);
    decode_clip(rv, w, h, cx, cy, bx);
    label = c;
  }
}

// ---------------- K1: softmax + decode + valid -> per-section slices --------
// 512 threads = 8 waves, ONE proposal per wave (R8 version)
__global__ __launch_bounds__(512) void
k1_score(const float* __restrict__ logits, const float* __restrict__ reg,
         const float* __restrict__ props, u64* __restrict__ slices,
         int* __restrict__ scnt) {
  int blk = blockIdx.x, t = threadIdx.x, lane = t & 63, wv = t >> 6;  // 0..7
  int b = blk / NSEC2, sec = blk % NSEC2;
  __shared__ u64 cbuf[SSLOT];
  __shared__ int cnt_sh;
  if (t == 0) cnt_sh = 0;
  __syncthreads();

  {
    int p = sec * SECP + wv;
    int wid = b * Pn + p;
    const float* lg = logits + (size_t)wid * Cn;
    float x0 = lg[lane];
    float x1 = (lane < Cn - 64) ? lg[64 + lane] : -3.4e38f;
    float mx = fmaxf(x0, x1);
    for (int m = 32; m; m >>= 1) mx = fmaxf(mx, __shfl_xor(mx, m, 64));
    float e0 = expf(x0 - mx);
    float e1 = (lane < Cn - 64) ? expf(x1 - mx) : 0.0f;
    float ssum = e0 + e1;
    for (int m = 32; m; m >>= 1) ssum += __shfl_xor(ssum, m, 64);

    const float4 pb = *reinterpret_cast<const float4*>(props + (size_t)wid * 4);
    float w = pb.z - pb.x, h = pb.w - pb.y;
    float cx = pb.x + 0.5f * w, cy = pb.y + 0.5f * h;
    const float* rrow = reg + (size_t)wid * (Cn * 4);

    u64 key0 = 0ull, key1 = 0ull;
    if (lane >= 1) {                     // class c = lane (1..63)
      float sc = e0 / ssum;
      if (sc > 0.05f) {
        float4 rv = *reinterpret_cast<const float4*>(rrow + lane * 4);
        float bx[4];
        decode_clip(rv, w, h, cx, cy, bx);
        if ((bx[2] - bx[0] >= 0.01f) && (bx[3] - bx[1] >= 0.01f)) {
          unsigned m = (unsigned)(p * CM1 + (lane - 1));
          key0 = ((u64)__float_as_uint(sc) << 32) | (0xFFFFFFFFu - m);
        }
      }
    }
    if (lane < Cn - 64) {                // class c = 64+lane (64..80)
      int c = 64 + lane;
      float sc = e1 / ssum;
      if (sc > 0.05f) {
        float4 rv = *reinterpret_cast<const float4*>(rrow + c * 4);
        float bx[4];
        decode_clip(rv, w, h, cx, cy, bx);
        if ((bx[2] - bx[0] >= 0.01f) && (bx[3] - bx[1] >= 0.01f)) {
          unsigned m = (unsigned)(p * CM1 + (c - 1));
          key1 = ((u64)__float_as_uint(sc) << 32) | (0xFFFFFFFFu - m);
        }
      }
    }
    u64 bal0 = __ballot(key0 != 0ull);
    u64 bal1 = __ballot(key1 != 0ull);
    int tot = __popcll(bal0) + __popcll(bal1);
    if (tot) {
      int base = 0;
      if (lane == 0) base = atomicAdd(&cnt_sh, tot);   // LDS atomic only
      base = __shfl(base, 0, 64);
      int r0 = __popcll(bal0 & ((1ull << lane) - 1ull));
      int r1 = __popcll(bal0) + __popcll(bal1 & ((1ull << lane) - 1ull));
      if (key0) cbuf[base + r0] = key0;
      if (key1) cbuf[base + r1] = key1;
    }
  }
  __syncthreads();
  int n = cnt_sh;                         // <= 152
  for (int i = t; i < n; i += 512) slices[(size_t)blk * SSLOT + i] = cbuf[i];
  if (t == 0) scnt[blk] = n;
}

// in-place reg-staged merge-path round over LDS (desc, A-priority, exact);
// used for the per-segment 4096 -> top-2048 truncation in k2b
template <int CHV>
__device__ __forceinline__ void mp_round(u64* buf, int base, int nA, int nB,
                                         int outLen, int tid) {
  const u64* A = buf + base;
  const u64* B = buf + base + nA;
  int d = tid * CHV;
  u64 rg[CHV];
  int cnt = 0;
  if (d < outLen) {
    int lo = max(0, d - nB), hi = min(d, nA);
    while (lo < hi) {
      int mid = (lo + hi) >> 1;
      if (A[mid] >= B[d - 1 - mid]) lo = mid + 1; else hi = mid;
    }
    int i = lo, j = d - lo;
    for (int e = 0; e < CHV && d + e < outLen; e++) {
      u64 v;
      if (j >= nB || (i < nA && A[i] >= B[j])) v = A[i++];
      else v = B[j++];
      rg[cnt++] = v;
    }
  }
  __syncthreads();
  for (int e = 0; e < cnt; e++) buf[base + d + e] = rg[e];
  __syncthreads();
}

// in-place merge round over a 4096-element LDS buffer: pairs of sorted len/2
// runs -> sorted len runs. CHV=4 keeps cursors 32 B apart (bank-spread).
template <int CHV>
__device__ __forceinline__ void mp_seg_round(u64* buf, int len, int cnt, int t) {
  int tps = len / CHV;           // threads per segment (1024*CHV == 4096)
  int seg = t / tps;
  int tid = t - seg * tps;
  int base = seg * len;
  bool act = (base < cnt);
  int nA = len >> 1;
  int d = tid * CHV;
  u64 rg[CHV];
  if (act) {
    const u64* A = buf + base;
    const u64* B = buf + base + nA;
    int lo = max(0, d - nA), hi = min(d, nA);
    while (lo < hi) {
      int mid = (lo + hi) >> 1;
      if (A[mid] >= B[d - 1 - mid]) lo = mid + 1; else hi = mid;
    }
    int i = lo, j = d - lo;
    #pragma unroll
    for (int e = 0; e < CHV; e++) {
      u64 v;
      if (j >= nA || (i < nA && A[i] >= B[j])) v = A[i++];
      else v = B[j++];
      rg[e] = v;
    }
  }
  __syncthreads();
  if (act) {
    #pragma unroll
    for (int e = 0; e < CHV; e++) buf[base + d + e] = rg[e];
  }
  __syncthreads();
}

// wave-level compacting append of one 64-wide chunk
__device__ __forceinline__ void append_chunk(u64 key, bool valid, u64* buf,
                                             int* cnt_sh, int lane) {
  u64 bal = __ballot(valid);
  int tot = __popcll(bal);
  if (tot) {
    int base = 0;
    if (lane == 0) base = atomicAdd(cnt_sh, tot);
    base = __shfl(base, 0, 64);
    int rank = __popcll(bal & ((1ull << lane) - 1ull));
    int pos = base + rank;
    if (valid && pos < K2CAP) buf[pos] = key;
  }
}

// ---------------- K2b: per-segment stream -> sort -> exact top-2048 run -----
// (R8 version) 32 blocks = 8 images x 4 segments.
__global__ __launch_bounds__(1024) void
k2b_sort(const u64* __restrict__ slices, const int* __restrict__ scnt,
         u64* __restrict__ runs) {
  int blk = blockIdx.x, t = threadIdx.x, lane = t & 63, w = t >> 6;  // 16 waves
  int b = blk >> 2, seg = blk & 3;
  int s0 = seg * 62 + min(seg, 2);        // 63,63,62,62 sections
  int ns = 62 + (seg < 2 ? 1 : 0);
  __shared__ u64 buf[K2CAP];              // 32 KB
  __shared__ int lcnt2[63];
  __shared__ int cnt_sh;
  if (t == 0) cnt_sh = 0;
  if (t < ns) lcnt2[t] = scnt[b * NSEC2 + s0 + t];
  __syncthreads();

  // prefetched stream of this segment's sections (16 waves, ~4 iters/wave)
  {
    int sl = w;
    int n0 = 0; u64 kv = 0ull;
    if (sl < ns) {
      n0 = lcnt2[sl];
      if (lane < n0) kv = slices[(size_t)(b * NSEC2 + s0 + sl) * SSLOT + lane];
    }
    while (sl < ns) {
      int nx = sl + 16;
      int n1 = 0; u64 kn = 0ull;
      if (nx < ns) {                      // issue next section's load NOW
        n1 = lcnt2[nx];
        if (lane < n1)
          kn = slices[(size_t)(b * NSEC2 + s0 + nx) * SSLOT + lane];
      }
      append_chunk(kv, (lane < n0) && (kv != 0ull), buf, &cnt_sh, lane);
      for (int i0 = 64; i0 < n0; i0 += 64) {   // sections with > 64 cands
        int i = i0 + lane;
        u64 ke = (i < n0) ? slices[(size_t)(b * NSEC2 + s0 + sl) * SSLOT + i]
                          : 0ull;
        append_chunk(ke, ke != 0ull, buf, &cnt_sh, lane);
      }
      sl = nx; n0 = n1; kv = kn;
    }
  }
  __syncthreads();
  int cnt = min(cnt_sh, K2CAP);
  for (int i = cnt + t; i < K2CAP; i += 1024) buf[i] = 0ull;
  __syncthreads();

  // 64-wide register bitonic sorts (desc), zero barriers
  for (int r = w; (r << 6) < cnt; r += 16) {
    u64 v = buf[(r << 6) | lane];
    #pragma unroll
    for (int k = 2; k <= 64; k <<= 1) {
      #pragma unroll
      for (int j = k >> 1; j > 0; j >>= 1) {
        u64 o = __shfl_xor(v, j, 64);
        bool dir = ((lane & k) == 0);      // descending block
        bool lower = ((lane & j) == 0);
        u64 mn = (v < o) ? v : o;
        u64 mx = (v < o) ? o : v;
        v = (dir == lower) ? mx : mn;
      }
    }
    buf[(r << 6) | lane] = v;
  }
  __syncthreads();

  // guarded merge tree 64 -> 2048, then truncate 4096 -> top-2048
  if (cnt > 64)   mp_seg_round<4>(buf, 128, cnt, t);
  if (cnt > 128)  mp_seg_round<4>(buf, 256, cnt, t);
  if (cnt > 256)  mp_seg_round<4>(buf, 512, cnt, t);
  if (cnt > 512)  mp_seg_round<4>(buf, 1024, cnt, t);
  if (cnt > 1024) mp_seg_round<4>(buf, 2048, cnt, t);
  if (cnt > 2048) mp_round<2>(buf, 0, 2048, 2048, 2048, t);

  // write the (zero-padded) sorted top-2048 run
  for (int i = t; i < RUNL; i += 1024)
    runs[(size_t)blk * RUNL + i] = buf[i];
}

// ---------------- K3: tournament merge -> top-2048 -> NMS -> out ------------
// Changes vs R8: (1) round 1 is TRUNCATING (tournament property: global
// top-2048 is contained in the union of per-pair top-2048s; keys unique so
// no tie ambiguity) -> 40% less merge work, bufD halves (LDS 136->105 KB).
// (2) boxes are decoded per NMS window on demand (256 at a time) instead of
// all 2048 upfront -> typically ~1500+ scattered gathers skipped.
__global__ __launch_bounds__(1024) void
k3_nms(const u64* __restrict__ runs, const float* __restrict__ reg,
       const float* __restrict__ props, float* __restrict__ out) {
  int b = blockIdx.x, t = threadIdx.x, lane = t & 63, w = t >> 6;  // 16 waves
  __shared__ u64 bufS[NSEG * RUNL];    // 64 KB (runs in; merged keys in [0,2048))
  __shared__ u64 bufD[2 * RUNL];       // 32 KB (round-1 out, then obox[2048])
  __shared__ u64 maskb[256][4];        // 8 KB
  __shared__ u64 keepw[KPRE / 64];     // 256 B
  __shared__ int accI[NDET];
  __shared__ int kcnt_sh;
  float4* obox = (float4*)bufD;

  // load 4 sorted runs, coalesced
  for (int i = t; i < NSEG * RUNL; i += 1024)
    bufS[i] = runs[(size_t)b * NSEG * RUNL + i];
  __syncthreads();

  // round 1: two TRUNCATING pair merges (2048+2048 -> top-2048), S -> D
  {
    int p = t >> 9;                    // pair 0 or 1 (512 threads each)
    int tid = t & 511;
    const u64* A = bufS + p * 4096;
    const u64* B = A + 2048;
    int d = tid * 4;                   // 512 x 4 = 2048 outputs per pair
    int lo = max(0, d - 2048), hi = min(d, 2048);
    while (lo < hi) {
      int mid = (lo + hi) >> 1;
      if (A[mid] >= B[d - 1 - mid]) lo = mid + 1; else hi = mid;
    }
    int i = lo, j = d - lo;
    #pragma unroll
    for (int e = 0; e < 4; e++) {
      u64 v;
      if (j >= 2048 || (i < 2048 && A[i] >= B[j])) v = A[i++];
      else v = B[j++];
      bufD[p * 2048 + d + e] = v;
    }
  }
  __syncthreads();
  // round 2: truncating merge (2048+2048 -> top-2048), D -> S[0..2048)
  {
    const u64* A = bufD;
    const u64* B = bufD + 2048;
    int d = t * 2;
    int lo = max(0, d - 2048), hi = min(d, 2048);
    while (lo < hi) {
      int mid = (lo + hi) >> 1;
      if (A[mid] >= B[d - 1 - mid]) lo = mid + 1; else hi = mid;
    }
    int i = lo, j = d - lo;
    #pragma unroll
    for (int e = 0; e < 2; e++) {
      u64 v;
      if (j >= 2048 || (i < 2048 && A[i] >= B[j])) v = A[i++];
      else v = B[j++];
      bufS[d + e] = v;                 // final keys in bufS[0..2048)
    }
  }
  __syncthreads();

  // keepw init from merged keys (bufD free after this barrier for obox)
  u64 k0 = bufS[t], k1v = bufS[t + 1024];
  {
    u64 bal = __ballot(k0 != 0ull);
    if (lane == 0) keepw[w] = bal;
    bal = __ballot(k1v != 0ull);
    if (lane == 0) keepw[16 + w] = bal;
  }
  __syncthreads();

  // windowed bitmask greedy NMS with early exit; per-window on-demand decode
  int kcount = 0;
  for (int w0 = 0; w0 < KPRE && kcount < NDET; w0 += 256) {
    // decode this window's 256 boxes (label-offset applied)
    if (t < 256) {
      int j = w0 + t;
      u64 key = bufS[j];
      float bx[4]; int label; float sc;
      key_decode(key, b, reg, props, bx, label, sc);
      float off = (float)label * NMS_OFF;
      obox[j] = make_float4(bx[0] + off, bx[1] + off, bx[2] + off, bx[3] + off);
    }
    __syncthreads();
    // step1: suppress window cols by previously accepted boxes
    if (w0 > 0 && kcount > 0) {
      if (t < 256) {
        int j = w0 + t;
        u64 kwv = keepw[j >> 6];
        bool alive = (kwv >> (j & 63)) & 1ull;
        if (alive) {
          float4 jb = obox[j];
          float jar = fmaxf(jb.z - jb.x, 0.0f) * fmaxf(jb.w - jb.y, 0.0f);
          for (int a = 0; a < kcount; a++) {
            float4 ab = obox[accI[a]];
            float ix1 = fmaxf(ab.x, jb.x), iy1 = fmaxf(ab.y, jb.y);
            float ix2 = fminf(ab.z, jb.z), iy2 = fminf(ab.w, jb.w);
            float iw = fmaxf(ix2 - ix1, 0.0f), ih = fmaxf(iy2 - iy1, 0.0f);
            float inter = iw * ih;
            if (inter > 0.0f) {
              float aar = fmaxf(ab.z - ab.x, 0.0f) * fmaxf(ab.w - ab.y, 0.0f);
              float iou = inter / fmaxf(aar + jar - inter, 1e-9f);
              if (iou > 0.5f) { alive = false; break; }
            }
          }
        }
        u64 bal = __ballot(alive);
        if (lane == 0) keepw[(w0 >> 6) + (t >> 6)] = bal;
      }
      __syncthreads();
    }
    // step2: window-internal suppression bitmask (row r = t>>2, word wd = t&3)
    {
      int r = t >> 2, wd = t & 3;
      int rgp = w0 + r;
      bool ralive = (keepw[rgp >> 6] >> (rgp & 63)) & 1ull;
      float4 rb = obox[rgp];
      float rar = fmaxf(rb.z - rb.x, 0.0f) * fmaxf(rb.w - rb.y, 0.0f);
      u64 m = 0;
      if (ralive) {
        int cb0 = w0 + wd * 64;
        for (int jj = 0; jj < 64; jj++) {
          int cg = cb0 + jj;
          float4 cb = obox[cg];
          float ix1 = fmaxf(rb.x, cb.x), iy1 = fmaxf(rb.y, cb.y);
          float ix2 = fminf(rb.z, cb.z), iy2 = fminf(rb.w, cb.w);
          float iw = fmaxf(ix2 - ix1, 0.0f), ih = fmaxf(iy2 - iy1, 0.0f);
          float inter = iw * ih;
          if (inter > 0.0f && cg > rgp) {
            float car = fmaxf(cb.z - cb.x, 0.0f) * fmaxf(cb.w - cb.y, 0.0f);
            float iou = inter / fmaxf(rar + car - inter, 1e-9f);
            if (iou > 0.5f) m |= (1ull << jj);
          }
        }
      }
      maskb[r][wd] = m;
    }
    __syncthreads();
    // step3: single-wave serial greedy reduce over the window
    if (w == 0) {
      u64 kw0 = keepw[(w0 >> 6) + 0];
      u64 kw1 = keepw[(w0 >> 6) + 1];
      u64 kw2 = keepw[(w0 >> 6) + 2];
      u64 kw3 = keepw[(w0 >> 6) + 3];
      int kc = kcount;
      #pragma unroll
      for (int wq = 0; wq < 4; wq++) {
        u64 cw = (wq == 0) ? kw0 : (wq == 1) ? kw1 : (wq == 2) ? kw2 : kw3;
        if (cw == 0ull) continue;
        for (int rb0 = 0; rb0 < 64 && kc < NDET; rb0 += 4) {
          u64 gbits = (cw >> rb0) & 0xFull;
          int r = wq * 64 + rb0;
          u64 rm0a = maskb[r][0],   rm0b = maskb[r][1],   rm0c = maskb[r][2],   rm0d = maskb[r][3];
          u64 rm1a = maskb[r+1][0], rm1b = maskb[r+1][1], rm1c = maskb[r+1][2], rm1d = maskb[r+1][3];
          u64 rm2a = maskb[r+2][0], rm2b = maskb[r+2][1], rm2c = maskb[r+2][2], rm2d = maskb[r+2][3];
          u64 rm3a = maskb[r+3][0], rm3b = maskb[r+3][1], rm3c = maskb[r+3][2], rm3d = maskb[r+3][3];
          if (gbits == 0ull) continue;
          #pragma unroll
          for (int d = 0; d < 4; d++) {
            u64 cwq = (wq == 0) ? kw0 : (wq == 1) ? kw1 : (wq == 2) ? kw2 : kw3;
            if ((cwq >> (rb0 + d)) & 1ull) {
              if (lane == 0) accI[kc] = w0 + r + d;
              kc++;
              if (kc >= NDET) break;
              u64 ma = (d == 0) ? rm0a : (d == 1) ? rm1a : (d == 2) ? rm2a : rm3a;
              u64 mb = (d == 0) ? rm0b : (d == 1) ? rm1b : (d == 2) ? rm2b : rm3b;
              u64 mc = (d == 0) ? rm0c : (d == 1) ? rm1c : (d == 2) ? rm2c : rm3c;
              u64 md = (d == 0) ? rm0d : (d == 1) ? rm1d : (d == 2) ? rm2d : rm3d;
              kw0 &= ~ma; kw1 &= ~mb; kw2 &= ~mc; kw3 &= ~md;
            }
          }
          cw = (wq == 0) ? kw0 : (wq == 1) ? kw1 : (wq == 2) ? kw2 : kw3;
        }
      }
      if (lane == 0) {
        keepw[(w0 >> 6) + 0] = kw0;
        keepw[(w0 >> 6) + 1] = kw1;
        keepw[(w0 >> 6) + 2] = kw2;
        keepw[(w0 >> 6) + 3] = kw3;
        kcnt_sh = kc;
      }
    }
    __syncthreads();
    kcount = kcnt_sh;
  }

  // rare path: fewer than 100 kept -> backfill non-kept ascending
  if (t == 0 && kcount < NDET) {
    int run = kcount;
    for (int wq = 0; wq < KPRE / 64 && run < NDET; wq++) {
      u64 nk = ~keepw[wq];
      while (nk && run < NDET) {
        int bit2 = __ffsll((long long)nk) - 1;
        nk &= nk - 1;
        accI[run++] = wq * 64 + bit2;
      }
    }
  }
  __syncthreads();

  if (t < NDET) {
    int k = accI[t];
    bool kept = t < kcount;
    u64 key = bufS[k];                     // final merged keys live in bufS
    float bx[4]; int label; float sc;
    key_decode(key, b, reg, props, bx, label, sc);
    int oi = b * NDET + t;
    out[(size_t)oi * 4 + 0] = bx[0];
    out[(size_t)oi * 4 + 1] = bx[1];
    out[(size_t)oi * 4 + 2] = bx[2];
    out[(size_t)oi * 4 + 3] = bx[3];
    out[Bn * NDET * 4 + oi] = kept ? sc : -1.0f;
    out[Bn * NDET * 5 + oi] = (float)label;
    out[Bn * NDET * 6 + oi] = kept ? 1.0f : 0.0f;
  }
}

extern "C" void kernel_launch(void* const* d_in, const int* in_sizes, int n_in,
                              void* d_out, int out_size, void* d_ws, size_t ws_size,
                              hipStream_t stream) {
  const float* logits = (const float*)d_in[0];
  const float* reg    = (const float*)d_in[1];
  const float* props  = (const float*)d_in[2];
  float* out = (float*)d_out;
  char* ws = (char*)d_ws;

  u64* slices = (u64*)(ws + OFF_SL);
  int* scnt   = (int*)(ws + OFF_SC);
  u64* runs   = (u64*)(ws + OFF_RUNS);

  k1_score<<<Bn * NSEC2, 512, 0, stream>>>(logits, reg, props, slices, scnt);
  k2b_sort<<<Bn * NSEG, 1024, 0, stream>>>(slices, scnt, runs);
  k3_nms<<<Bn, 1024, 0, stream>>>(runs, reg, props, out);
}